// Round 9
// baseline (1263.457 us; speedup 1.0000x reference)
//
#include <hip/hip_runtime.h>
#include <hip/hip_fp16.h>

#define NB   256
#define TT   1024
#define II   64
#define NT   256

typedef _Float16 f16;
typedef _Float16 f16x4 __attribute__((ext_vector_type(4)));
typedef _Float16 hf8 __attribute__((ext_vector_type(8)));
typedef float    ff4 __attribute__((ext_vector_type(4)));

__device__ __forceinline__ float rcp_fast(float x){
    float r; asm("v_rcp_f32 %0, %1" : "=v"(r) : "v"(x)); return r;
}
__device__ __forceinline__ float exp2_fast(float x){
    float r; asm("v_exp_f32 %0, %1" : "=v"(r) : "v"(x)); return r;
}
__device__ __forceinline__ float sigm(float x){
    return rcp_fast(1.0f + exp2_fast(x * -1.44269504f));
}
__device__ __forceinline__ float tanh_f(float x){
    return fmaf(-2.0f, rcp_fast(1.0f + exp2_fast(x * 2.88539008f)), 1.0f);
}

// 4 waves x 12 tiles (16 rows each), gate-interleaved rows (unit 4*tau+(rho>>2),
// gate rho&3). Tiles 0-31: L1 (K=192 over [x;h1]); 32-47: L2 (K=192 over [h1;h2]).
// Wave w owns tiles 12w..12w+11 (waves 0,1: pure L1; wave 2: 8 L1 + 4 L2; wave 3: L2).
// A-frags (12x6 hf8 = 288 regs) parked in unified VGPR/AGPR file, 1 wave/SIMD.
// B-frag window per step (per lane): frags m at {x: m0,m1} {h1: m2..m5} {h2: m6,m7};
// L1 tile uses frag kt, L2 tile uses frag kt+2. 26 ds_read_b128/step/block.
// C/D: col=lane&15 (16 duplicate cols), row=(lane>>4)*4+reg [m89, verified R5-R8]
// => lane's 4 acc regs of tile i hold gates i,f,g,o of unit 4*tau_i+kg.
// Lane rho<12 activates tile i=rho (select via cndmask tree, static indexing).

__launch_bounds__(NT, 1)
__global__ void lstm_mfma(const float* __restrict__ x,
                          const float* __restrict__ Wih1, const float* __restrict__ Whh1,
                          const float* __restrict__ bih1, const float* __restrict__ bhh1,
                          const float* __restrict__ Wih2, const float* __restrict__ Whh2,
                          const float* __restrict__ bih2, const float* __restrict__ bhh2,
                          const float* __restrict__ W1,   const float* __restrict__ b1,
                          const float* __restrict__ W2,   const float* __restrict__ b2,
                          float* __restrict__ out)
{
    __shared__ __align__(16) f16 xchunk[64][II];   // 8 KB, x_t in row t&63
    __shared__ __align__(16) f16 h1buf[2][128];
    __shared__ __align__(16) f16 h2buf[2][64];
    __shared__ float headbuf[32];

    const int j    = threadIdx.x;      // 0..255
    const int b    = blockIdx.x;
    const int wave = j >> 6;           // 0..3
    const int lane = j & 63;
    const int rho  = lane & 15;
    const int kg   = lane >> 4;        // 0..3

    // ---------- one-time: A fragments + biases ----------
    hf8 A[12][6];
    ff4 bias[12];
    #pragma unroll
    for (int i = 0; i < 12; ++i){
        const int  tau = 12*wave + i;
        const bool l2  = (tau >= 32);
        #pragma unroll
        for (int kt = 0; kt < 6; ++kt){
            const int k = 32*kt + kg*8;
            const float* src;
            if (!l2){
                const int R = (rho & 3)*128 + 4*tau + (rho >> 2);
                src = (k < 64) ? (Wih1 + R*64 + k) : (Whh1 + R*128 + (k - 64));
            } else {
                const int R = (rho & 3)*64 + 4*(tau - 32) + (rho >> 2);
                src = (k < 128) ? (Wih2 + R*128 + k) : (Whh2 + R*64 + (k - 128));
            }
            float4 v0 = *(const float4*)src;
            float4 v1 = *(const float4*)(src + 4);
            hf8 a;
            a[0]=(f16)v0.x; a[1]=(f16)v0.y; a[2]=(f16)v0.z; a[3]=(f16)v0.w;
            a[4]=(f16)v1.x; a[5]=(f16)v1.y; a[6]=(f16)v1.z; a[7]=(f16)v1.w;
            A[i][kt] = a;
        }
        #pragma unroll
        for (int r = 0; r < 4; ++r){
            if (!l2){ const int R = r*128 + 4*tau + kg;        bias[i][r] = bih1[R] + bhh1[R]; }
            else    { const int R = r*64  + 4*(tau - 32) + kg; bias[i][r] = bih2[R] + bhh2[R]; }
        }
    }

    const int  myTau = 12*wave + rho;              // valid for rho<12
    const bool isl2  = (myTau >= 32);
    const int  myU   = isl2 ? 4*(myTau - 32) + kg : 4*myTau + kg;
    float c = 0.0f;

    const float* xb = x + (size_t)b * TT * II;

    // prologue: stage steps 0..31 into rows 0..31; zero h1,h2
    {
        const float4* sp = (const float4*)xb;
        float4 v0 = sp[2*j], v1 = sp[2*j + 1];
        hf8 w;
        w[0]=(f16)v0.x; w[1]=(f16)v0.y; w[2]=(f16)v0.z; w[3]=(f16)v0.w;
        w[4]=(f16)v1.x; w[5]=(f16)v1.y; w[6]=(f16)v1.z; w[7]=(f16)v1.w;
        *(hf8*)&xchunk[j >> 3][(j & 7)*8] = w;
        if (j < 128) h1buf[0][j] = (f16)0.0f;
        if (j < 64)  h2buf[0][j] = (f16)0.0f;
    }
    __syncthreads();

    int cur = 0;
    for (int t = 0; t < TT; ++t){
        // chunk staging: once per 32 steps, issue loads early
        const bool stage = ((t & 31) == 0) && (t + 32 < TT);
        float4 sv0, sv1;
        if (stage){
            const float4* sp = (const float4*)(xb + (size_t)(t + 32)*II);
            sv0 = sp[2*j]; sv1 = sp[2*j + 1];
        }

        const f16* xr  = xchunk[t & 63];
        const f16* h1c = h1buf[cur];
        const f16* h2c = h2buf[cur];

        // ---- B fragments (per-wave window) ----
        hf8 bf[8];
        if (wave <= 2){
            bf[0] = *(const hf8*)(xr + kg*8);
            bf[1] = *(const hf8*)(xr + 32 + kg*8);
        }
        bf[2] = *(const hf8*)(h1c       + kg*8);
        bf[3] = *(const hf8*)(h1c + 32  + kg*8);
        bf[4] = *(const hf8*)(h1c + 64  + kg*8);
        bf[5] = *(const hf8*)(h1c + 96  + kg*8);
        if (wave >= 2){
            bf[6] = *(const hf8*)(h2c      + kg*8);
            bf[7] = *(const hf8*)(h2c + 32 + kg*8);
        }

        // ---- MFMA: 12 tiles x 6 kt ----
        ff4 acc[12];
        #pragma unroll
        for (int i = 0; i < 12; ++i) acc[i] = bias[i];

        if (wave < 2){
            #pragma unroll
            for (int kt = 0; kt < 6; ++kt){
                hf8 bb = bf[kt];
                #pragma unroll
                for (int i = 0; i < 12; ++i)
                    acc[i] = __builtin_amdgcn_mfma_f32_16x16x32_f16(A[i][kt], bb, acc[i], 0, 0, 0);
            }
        } else if (wave == 2){
            #pragma unroll
            for (int kt = 0; kt < 6; ++kt){
                hf8 b1f = bf[kt];
                #pragma unroll
                for (int i = 0; i < 8; ++i)
                    acc[i] = __builtin_amdgcn_mfma_f32_16x16x32_f16(A[i][kt], b1f, acc[i], 0, 0, 0);
                hf8 b2f = bf[kt + 2];
                #pragma unroll
                for (int i = 8; i < 12; ++i)
                    acc[i] = __builtin_amdgcn_mfma_f32_16x16x32_f16(A[i][kt], b2f, acc[i], 0, 0, 0);
            }
        } else {
            #pragma unroll
            for (int kt = 0; kt < 6; ++kt){
                hf8 bb = bf[kt + 2];
                #pragma unroll
                for (int i = 0; i < 12; ++i)
                    acc[i] = __builtin_amdgcn_mfma_f32_16x16x32_f16(A[i][kt], bb, acc[i], 0, 0, 0);
            }
        }

        // ---- select own tile's quad (cndmask tree, rho<12) ----
        ff4 m0 = (rho & 1) ? acc[1]  : acc[0];
        ff4 m1 = (rho & 1) ? acc[3]  : acc[2];
        ff4 m2 = (rho & 1) ? acc[5]  : acc[4];
        ff4 m3 = (rho & 1) ? acc[7]  : acc[6];
        ff4 m4 = (rho & 1) ? acc[9]  : acc[8];
        ff4 m5 = (rho & 1) ? acc[11] : acc[10];
        ff4 n0 = (rho & 2) ? m1 : m0;
        ff4 n1 = (rho & 2) ? m3 : m2;
        ff4 n2 = (rho & 2) ? m5 : m4;
        ff4 p  = (rho & 4) ? n1 : n0;
        ff4 qd = (rho & 8) ? n2 : p;

        // ---- in-lane activation ----
        float hv;
        if (isl2 && t == 0){
            hv = 0.0f;                     // h2_{-1}=0, c2 untouched
        } else {
            float ig = sigm(qd[0]);
            float fg = sigm(qd[1]);
            float gg = tanh_f(qd[2]);
            float og = sigm(qd[3]);
            c  = fg*c + ig*gg;
            hv = og * tanh_f(c);
        }
        if (rho < 12){
            if (isl2) h2buf[cur ^ 1][myU] = (f16)hv;
            else      h1buf[cur ^ 1][myU] = (f16)hv;
        }

        // staging publish (vm-wait lands here, overlapped with step compute)
        if (stage){
            hf8 w;
            w[0]=(f16)sv0.x; w[1]=(f16)sv0.y; w[2]=(f16)sv0.z; w[3]=(f16)sv0.w;
            w[4]=(f16)sv1.x; w[5]=(f16)sv1.y; w[6]=(f16)sv1.z; w[7]=(f16)sv1.w;
            *(hf8*)&xchunk[((t + 32) & 63) + (j >> 3)][(j & 7)*8] = w;
        }
        __syncthreads();
        cur ^= 1;
    }
    // after loop: cur==0; h1buf[0]=h1_{TT-1}, h2buf[0]=h2_{TT-2}

    // ---- epilogue: L2 step TT-1 ----
    if (wave >= 2){
        const f16* h1c = h1buf[0];
        const f16* h2c = h2buf[0];
        hf8 ebf[6];
        ebf[0] = *(const hf8*)(h1c      + kg*8);
        ebf[1] = *(const hf8*)(h1c + 32 + kg*8);
        ebf[2] = *(const hf8*)(h1c + 64 + kg*8);
        ebf[3] = *(const hf8*)(h1c + 96 + kg*8);
        ebf[4] = *(const hf8*)(h2c      + kg*8);
        ebf[5] = *(const hf8*)(h2c + 32 + kg*8);

        ff4 acc[12];
        #pragma unroll
        for (int i = 0; i < 12; ++i) acc[i] = bias[i];
        if (wave == 2){
            #pragma unroll
            for (int kt = 0; kt < 6; ++kt){
                hf8 bb = ebf[kt];
                #pragma unroll
                for (int i = 8; i < 12; ++i)
                    acc[i] = __builtin_amdgcn_mfma_f32_16x16x32_f16(A[i][kt], bb, acc[i], 0, 0, 0);
            }
        } else {
            #pragma unroll
            for (int kt = 0; kt < 6; ++kt){
                hf8 bb = ebf[kt];
                #pragma unroll
                for (int i = 0; i < 12; ++i)
                    acc[i] = __builtin_amdgcn_mfma_f32_16x16x32_f16(A[i][kt], bb, acc[i], 0, 0, 0);
            }
        }
        ff4 m0 = (rho & 1) ? acc[1]  : acc[0];
        ff4 m1 = (rho & 1) ? acc[3]  : acc[2];
        ff4 m2 = (rho & 1) ? acc[5]  : acc[4];
        ff4 m3 = (rho & 1) ? acc[7]  : acc[6];
        ff4 m4 = (rho & 1) ? acc[9]  : acc[8];
        ff4 m5 = (rho & 1) ? acc[11] : acc[10];
        ff4 n0 = (rho & 2) ? m1 : m0;
        ff4 n1 = (rho & 2) ? m3 : m2;
        ff4 n2 = (rho & 2) ? m5 : m4;
        ff4 p  = (rho & 4) ? n1 : n0;
        ff4 qd = (rho & 8) ? n2 : p;

        if (rho < 12 && isl2){
            float ig = sigm(qd[0]);
            float fg = sigm(qd[1]);
            float gg = tanh_f(qd[2]);
            float og = sigm(qd[3]);
            c = fg*c + ig*gg;
            float hv = og * tanh_f(c);
            h2buf[1][myU] = (f16)hv;
        }
    }
    __syncthreads();

    // ---- MLP head (final h2 in h2buf[1]) ----
    if (j < 32){
        float a = b1[j];
        const float* w = W1 + j*64;
        #pragma unroll
        for (int k = 0; k < 64; ++k) a = fmaf(w[k], (float)h2buf[1][k], a);
        headbuf[j] = sigm(a);
    }
    __syncthreads();
    if (j == 0){
        float a = b2[0];
        #pragma unroll
        for (int k = 0; k < 32; ++k) a = fmaf(W2[k], headbuf[k], a);
        out[b] = sigm(a);
    }
}

extern "C" void kernel_launch(void* const* d_in, const int* in_sizes, int n_in,
                              void* d_out, int out_size, void* d_ws, size_t ws_size,
                              hipStream_t stream)
{
    (void)in_sizes; (void)n_in; (void)d_ws; (void)ws_size; (void)out_size;
    lstm_mfma<<<NB, NT, 0, stream>>>(
        (const float*)d_in[0],
        (const float*)d_in[1], (const float*)d_in[2],
        (const float*)d_in[3], (const float*)d_in[4],
        (const float*)d_in[5], (const float*)d_in[6],
        (const float*)d_in[7], (const float*)d_in[8],
        (const float*)d_in[9], (const float*)d_in[10],
        (const float*)d_in[11], (const float*)d_in[12],
        (float*)d_out);
}

// Round 10
// 945.582 us; speedup vs baseline: 1.3362x; 1.3362x over previous
//
#include <hip/hip_runtime.h>
#include <hip/hip_fp16.h>

#define NB   256
#define TT   1024
#define II   64
#define NT   512

typedef _Float16 f16;
typedef _Float16 f16x4 __attribute__((ext_vector_type(4)));
typedef _Float16 hf8 __attribute__((ext_vector_type(8)));
typedef float    ff4 __attribute__((ext_vector_type(4)));

__device__ __forceinline__ float rcp_fast(float x){
    float r; asm("v_rcp_f32 %0, %1" : "=v"(r) : "v"(x)); return r;
}
__device__ __forceinline__ float exp2_fast(float x){
    float r; asm("v_exp_f32 %0, %1" : "=v"(r) : "v"(x)); return r;
}
__device__ __forceinline__ float sigm(float x){
    return rcp_fast(1.0f + exp2_fast(x * -1.44269504f));
}
__device__ __forceinline__ float tanh_f(float x){
    return fmaf(-2.0f, rcp_fast(1.0f + exp2_fast(x * 2.88539008f)), 1.0f);
}

// 8 waves x 6 tiles (16 gate-interleaved rows each). Tiles 0-31: L1 (K=192
// over [x;h1]); 32-47: L2 (K=192 over [h1;h2]). Wave w owns tiles 6w..6w+5:
// waves 0-4 pure L1, wave 5 = 2 L1 + 4 L2, waves 6-7 pure L2.
// A-frags: A[6][6] hf8 = 144 VGPR/thread, parked in unified VGPR/AGPR file,
// 2 waves/SIMD (launch_bounds(512,2) -> 256-reg cap, ~250 used, no spill).
// B-frag window per lane: {x: bf0,bf1} {h1: bf2..bf5} {h2: bf6,bf7};
// L1 tile kt -> bf[kt], L2 tile kt -> bf[kt+2]. ~50 ds_read_b128/step/CU.
// C/D: col=lane&15 (16 dup cols), row=(lane>>4)*4+reg [m89, verified R5-R9]
// => lane (kg=lane>>4, rho=lane&15) holds gates i,f,g,o of unit 4*tau_i+kg
// in acc[i]; lane rho<6 activates tile i=rho (static cndmask tree).
// x pipeline: xchunk[64][64] f16 ring, staged 32 steps at a time (loads
// issued at top of stage step, published after compute).

__launch_bounds__(NT, 2)
__global__ void lstm_mfma(const float* __restrict__ x,
                          const float* __restrict__ Wih1, const float* __restrict__ Whh1,
                          const float* __restrict__ bih1, const float* __restrict__ bhh1,
                          const float* __restrict__ Wih2, const float* __restrict__ Whh2,
                          const float* __restrict__ bih2, const float* __restrict__ bhh2,
                          const float* __restrict__ W1,   const float* __restrict__ b1,
                          const float* __restrict__ W2,   const float* __restrict__ b2,
                          float* __restrict__ out)
{
    __shared__ __align__(16) f16 xchunk[64][II];   // 8 KB
    __shared__ __align__(16) f16 h1buf[2][128];
    __shared__ __align__(16) f16 h2buf[2][64];
    __shared__ float headbuf[32];

    const int j    = threadIdx.x;      // 0..511
    const int b    = blockIdx.x;
    const int wave = j >> 6;           // 0..7
    const int lane = j & 63;
    const int rho  = lane & 15;
    const int kg   = lane >> 4;        // 0..3

    // ---------- one-time: A fragments + biases ----------
    hf8 A[6][6];
    ff4 bias[6];
    #pragma unroll
    for (int i = 0; i < 6; ++i){
        const int  tau = 6*wave + i;
        const bool l2  = (tau >= 32);
        #pragma unroll
        for (int kt = 0; kt < 6; ++kt){
            const int k = 32*kt + kg*8;
            const float* src;
            if (!l2){
                const int R = (rho & 3)*128 + 4*tau + (rho >> 2);
                src = (k < 64) ? (Wih1 + R*64 + k) : (Whh1 + R*128 + (k - 64));
            } else {
                const int R = (rho & 3)*64 + 4*(tau - 32) + (rho >> 2);
                src = (k < 128) ? (Wih2 + R*128 + k) : (Whh2 + R*64 + (k - 128));
            }
            float4 v0 = *(const float4*)src;
            float4 v1 = *(const float4*)(src + 4);
            hf8 a;
            a[0]=(f16)v0.x; a[1]=(f16)v0.y; a[2]=(f16)v0.z; a[3]=(f16)v0.w;
            a[4]=(f16)v1.x; a[5]=(f16)v1.y; a[6]=(f16)v1.z; a[7]=(f16)v1.w;
            A[i][kt] = a;
        }
        #pragma unroll
        for (int r = 0; r < 4; ++r){
            if (!l2){ const int R = r*128 + 4*tau + kg;        bias[i][r] = bih1[R] + bhh1[R]; }
            else    { const int R = r*64  + 4*(tau - 32) + kg; bias[i][r] = bih2[R] + bhh2[R]; }
        }
    }

    const int  myTau = 6*wave + rho;               // valid for rho<6
    const bool isl2  = (myTau >= 32);
    const int  myU   = isl2 ? 4*(myTau - 32) + kg : 4*myTau + kg;
    float c = 0.0f;

    const float* xb = x + (size_t)b * TT * II;

    // prologue: stage steps 0..31 (8 KB fp32 = 512 float4, one per thread)
    {
        float4 v = ((const float4*)xb)[j];
        f16x4 w; w[0]=(f16)v.x; w[1]=(f16)v.y; w[2]=(f16)v.z; w[3]=(f16)v.w;
        *(f16x4*)&xchunk[j >> 4][(j & 15)*4] = w;
        if (j < 128) h1buf[0][j] = (f16)0.0f;
        if (j < 64)  h2buf[0][j] = (f16)0.0f;
    }
    __syncthreads();

    int cur = 0;
    for (int t = 0; t < TT; ++t){
        // chunk staging: once per 32 steps, issue loads early
        const bool stage = ((t & 31) == 0) && (t + 32 < TT);
        float4 sv;
        if (stage)
            sv = ((const float4*)(xb + (size_t)(t + 32)*II))[j];

        const f16* xr  = xchunk[t & 63];
        const f16* h1c = h1buf[cur];
        const f16* h2c = h2buf[cur];

        // ---- B fragments (per-wave window) ----
        hf8 bf[8];
        if (wave <= 5){
            bf[0] = *(const hf8*)(xr + kg*8);
            bf[1] = *(const hf8*)(xr + 32 + kg*8);
        }
        bf[2] = *(const hf8*)(h1c       + kg*8);
        bf[3] = *(const hf8*)(h1c + 32  + kg*8);
        bf[4] = *(const hf8*)(h1c + 64  + kg*8);
        bf[5] = *(const hf8*)(h1c + 96  + kg*8);
        if (wave >= 5){
            bf[6] = *(const hf8*)(h2c      + kg*8);
            bf[7] = *(const hf8*)(h2c + 32 + kg*8);
        }

        // ---- MFMA: 6 tiles x 6 kt ----
        ff4 acc[6];
        #pragma unroll
        for (int i = 0; i < 6; ++i) acc[i] = bias[i];

        if (wave < 5){
            #pragma unroll
            for (int kt = 0; kt < 6; ++kt){
                hf8 bb = bf[kt];
                #pragma unroll
                for (int i = 0; i < 6; ++i)
                    acc[i] = __builtin_amdgcn_mfma_f32_16x16x32_f16(A[i][kt], bb, acc[i], 0, 0, 0);
            }
        } else if (wave == 5){
            #pragma unroll
            for (int kt = 0; kt < 6; ++kt){
                hf8 b1f = bf[kt];
                acc[0] = __builtin_amdgcn_mfma_f32_16x16x32_f16(A[0][kt], b1f, acc[0], 0, 0, 0);
                acc[1] = __builtin_amdgcn_mfma_f32_16x16x32_f16(A[1][kt], b1f, acc[1], 0, 0, 0);
                hf8 b2f = bf[kt + 2];
                #pragma unroll
                for (int i = 2; i < 6; ++i)
                    acc[i] = __builtin_amdgcn_mfma_f32_16x16x32_f16(A[i][kt], b2f, acc[i], 0, 0, 0);
            }
        } else {
            #pragma unroll
            for (int kt = 0; kt < 6; ++kt){
                hf8 bb = bf[kt + 2];
                #pragma unroll
                for (int i = 0; i < 6; ++i)
                    acc[i] = __builtin_amdgcn_mfma_f32_16x16x32_f16(A[i][kt], bb, acc[i], 0, 0, 0);
            }
        }

        // ---- select own tile's quad (static cndmask tree, rho<6) ----
        ff4 m0 = (rho & 1) ? acc[1] : acc[0];
        ff4 m1 = (rho & 1) ? acc[3] : acc[2];
        ff4 m2 = (rho & 1) ? acc[5] : acc[4];
        ff4 n0 = (rho & 2) ? m1 : m0;
        ff4 qd = (rho & 4) ? m2 : n0;

        // ---- in-lane activation ----
        float hv;
        if (isl2 && t == 0){
            hv = 0.0f;                     // h2_{-1}=0, c2 untouched
        } else {
            float ig = sigm(qd[0]);
            float fg = sigm(qd[1]);
            float gg = tanh_f(qd[2]);
            float og = sigm(qd[3]);
            c  = fg*c + ig*gg;
            hv = og * tanh_f(c);
        }
        if (rho < 6){
            if (isl2) h2buf[cur ^ 1][myU] = (f16)hv;
            else      h1buf[cur ^ 1][myU] = (f16)hv;
        }

        // staging publish (vm-wait lands here, overlapped with step compute)
        if (stage){
            f16x4 w; w[0]=(f16)sv.x; w[1]=(f16)sv.y; w[2]=(f16)sv.z; w[3]=(f16)sv.w;
            *(f16x4*)&xchunk[((t + 32) & 63) + (j >> 4)][(j & 15)*4] = w;
        }
        __syncthreads();
        cur ^= 1;
    }
    // after loop: cur==0; h1buf[0]=h1_{TT-1}, h2buf[0]=h2_{TT-2}

    // ---- epilogue: L2 step TT-1 (waves 5-7) ----
    if (wave >= 5){
        const f16* h1c = h1buf[0];
        const f16* h2c = h2buf[0];
        hf8 ebf[6];
        ebf[0] = *(const hf8*)(h1c      + kg*8);
        ebf[1] = *(const hf8*)(h1c + 32 + kg*8);
        ebf[2] = *(const hf8*)(h1c + 64 + kg*8);
        ebf[3] = *(const hf8*)(h1c + 96 + kg*8);
        ebf[4] = *(const hf8*)(h2c      + kg*8);
        ebf[5] = *(const hf8*)(h2c + 32 + kg*8);

        ff4 acc[6];
        #pragma unroll
        for (int i = 0; i < 6; ++i) acc[i] = bias[i];
        if (wave == 5){
            #pragma unroll
            for (int kt = 0; kt < 6; ++kt){
                hf8 bb = ebf[kt];
                #pragma unroll
                for (int i = 2; i < 6; ++i)
                    acc[i] = __builtin_amdgcn_mfma_f32_16x16x32_f16(A[i][kt], bb, acc[i], 0, 0, 0);
            }
        } else {
            #pragma unroll
            for (int kt = 0; kt < 6; ++kt){
                hf8 bb = ebf[kt];
                #pragma unroll
                for (int i = 0; i < 6; ++i)
                    acc[i] = __builtin_amdgcn_mfma_f32_16x16x32_f16(A[i][kt], bb, acc[i], 0, 0, 0);
            }
        }
        ff4 m0 = (rho & 1) ? acc[1] : acc[0];
        ff4 m1 = (rho & 1) ? acc[3] : acc[2];
        ff4 m2 = (rho & 1) ? acc[5] : acc[4];
        ff4 n0 = (rho & 2) ? m1 : m0;
        ff4 qd = (rho & 4) ? m2 : n0;

        if (rho < 6 && isl2){
            float ig = sigm(qd[0]);
            float fg = sigm(qd[1]);
            float gg = tanh_f(qd[2]);
            float og = sigm(qd[3]);
            c = fg*c + ig*gg;
            float hv = og * tanh_f(c);
            h2buf[1][myU] = (f16)hv;
        }
    }
    __syncthreads();

    // ---- MLP head (final h2 in h2buf[1]) ----
    if (j < 32){
        float a = b1[j];
        const float* w = W1 + j*64;
        #pragma unroll
        for (int k = 0; k < 64; ++k) a = fmaf(w[k], (float)h2buf[1][k], a);
        headbuf[j] = sigm(a);
    }
    __syncthreads();
    if (j == 0){
        float a = b2[0];
        #pragma unroll
        for (int k = 0; k < 32; ++k) a = fmaf(W2[k], headbuf[k], a);
        out[b] = sigm(a);
    }
}

extern "C" void kernel_launch(void* const* d_in, const int* in_sizes, int n_in,
                              void* d_out, int out_size, void* d_ws, size_t ws_size,
                              hipStream_t stream)
{
    (void)in_sizes; (void)n_in; (void)d_ws; (void)ws_size; (void)out_size;
    lstm_mfma<<<NB, NT, 0, stream>>>(
        (const float*)d_in[0],
        (const float*)d_in[1], (const float*)d_in[2],
        (const float*)d_in[3], (const float*)d_in[4],
        (const float*)d_in[5], (const float*)d_in[6],
        (const float*)d_in[7], (const float*)d_in[8],
        (const float*)d_in[9], (const float*)d_in[10],
        (const float*)d_in[11], (const float*)d_in[12],
        (float*)d_out);
}